// Round 1
// baseline (102.988 us; speedup 1.0000x reference)
//
#include <hip/hip_runtime.h>
#include <hip/hip_bf16.h>

#define B_N 32
#define T_N 512
#define D_N 512
#define H_N 512
#define M_N (B_N * T_N)   // 16384

typedef __attribute__((ext_vector_type(8))) short bf16x8;
typedef __attribute__((ext_vector_type(4))) float f32x4;

__device__ __forceinline__ unsigned short f2bf(float f) {
  unsigned u = __float_as_uint(f);
  u += 0x7FFFu + ((u >> 16) & 1u);   // RTNE
  return (unsigned short)(u >> 16);
}
__device__ __forceinline__ float bf2f(unsigned short h) {
  return __uint_as_float(((unsigned)h) << 16);
}

#define GLOAD16(g, l) __builtin_amdgcn_global_load_lds( \
    (const __attribute__((address_space(1))) void*)(g), \
    (__attribute__((address_space(3))) void*)(l), 16, 0, 0)

// ---------------------------------------------------------------------------
// prep: blocks [0,768) transpose+convert the 3 weight matrices (W[k][n] ->
// Wt[id][n][k] bf16); blocks [768, 2816) convert x f32 -> bf16.
// ---------------------------------------------------------------------------
__global__ void prep_kernel(const float* __restrict__ x,
                            const float* __restrict__ W0,
                            const float* __restrict__ W1,
                            const float* __restrict__ W2,
                            unsigned short* __restrict__ xb,
                            unsigned short* __restrict__ Wt) {
  int blk = blockIdx.x;
  int tid = threadIdx.x;
  if (blk < 768) {
    __shared__ float tile[32][33];
    int id = blk >> 8;
    int t = blk & 255;
    int kr = (t >> 4) << 5;
    int nc = (t & 15) << 5;
    const float* W = (id == 0) ? W0 : (id == 1) ? W1 : W2;
    unsigned short* Wo = Wt + (size_t)id * (D_N * H_N);
    int tx = tid & 31, ty0 = tid >> 5;
    for (int ty = ty0; ty < 32; ty += 8)
      tile[ty][tx] = W[(size_t)(kr + ty) * H_N + nc + tx];
    __syncthreads();
    for (int ty = ty0; ty < 32; ty += 8)
      Wo[(size_t)(nc + ty) * D_N + kr + tx] = f2bf(tile[tx][ty]);
  } else {
    int b = blk - 768;
    const float4* xv = (const float4*)x;
#pragma unroll
    for (int u = 0; u < 4; ++u) {
      int i = b * 1024 + u * 256 + tid;
      float4 v = xv[i];
      ushort4 o;
      o.x = f2bf(v.x); o.y = f2bf(v.y); o.z = f2bf(v.z); o.w = f2bf(v.w);
      ((ushort4*)xb)[i] = o;
    }
  }
}

// ---------------------------------------------------------------------------
// gemm_act: one block = 64 rows x full N=512 for one of the 3 projections.
// BK=64, 8 waves (2x4 over 32-row x 128-col wave tiles).
// LDS tiles are XOR-swizzled (slot ^= row&7 of 16B slots, 128B rows) to make
// ds_read_b128 bank-conflict-free; the matching inverse permutation is applied
// to the per-lane GLOBAL source address of global_load_lds (linear LDS dest).
// Epilogue fuses bias + tanh (id 0) or bias + softmax (id 1,2).
// ---------------------------------------------------------------------------
__global__ __launch_bounds__(512) void gemm_act(
    const unsigned short* __restrict__ xb,
    const unsigned short* __restrict__ Wt,
    const float* __restrict__ bDu,
    const float* __restrict__ bDr1,
    const float* __restrict__ bDr2,
    float* __restrict__ uP,
    unsigned short* __restrict__ r1P,
    unsigned short* __restrict__ r2P) {
  __shared__ __align__(16) unsigned short lA[64 * 64];
  __shared__ __align__(16) unsigned short lB[512 * 64];
  __shared__ __align__(16) float red[64][4];
  __shared__ __align__(16) float red2[64][4];

  const int tid = threadIdx.x;
  const int lane = tid & 63;
  const int wv = tid >> 6;
  const int wm = wv >> 2;   // 0..1  (row half)
  const int wn = wv & 3;    // 0..3  (col quarter)
  const int g = lane >> 4;  // 0..3
  const int c16 = lane & 15;

  const int m0 = blockIdx.x * 64;
  const int id = blockIdx.y;
  const unsigned short* Wp = Wt + (size_t)id * (D_N * H_N);

  f32x4 acc[2][8];
#pragma unroll
  for (int mt = 0; mt < 2; ++mt)
#pragma unroll
    for (int nt = 0; nt < 8; ++nt)
      acc[mt][nt] = (f32x4){0.f, 0.f, 0.f, 0.f};

  // A staging: 512 16B-chunks, one global_load_lds per wave per K-step.
  const int cwA = wv * 64 + lane;
  const int rowA = cwA >> 3;
  const int slA = ((cwA & 7) ^ (rowA & 7)) << 3;  // inverse-swizzled k-slot (elems)
  char* ldsA_dst = (char*)lA + (size_t)wv * 1024;

  for (int kk = 0; kk < 8; ++kk) {
    const int k0 = kk * 64;
    GLOAD16(xb + (size_t)(m0 + rowA) * D_N + k0 + slA, ldsA_dst);
#pragma unroll
    for (int jj = 0; jj < 8; ++jj) {
      int cb = wv * 512 + jj * 64 + lane;
      int n = cb >> 3;
      int sl = ((cb & 7) ^ (n & 7)) << 3;
      GLOAD16(Wp + (size_t)n * D_N + k0 + sl,
              (char*)lB + (size_t)(wv * 512 + jj * 64) * 16);
    }
    asm volatile("s_waitcnt vmcnt(0)" ::: "memory");
    __syncthreads();
#pragma unroll
    for (int kh = 0; kh < 2; ++kh) {
      bf16x8 af[2], bfr[8];
#pragma unroll
      for (int mt = 0; mt < 2; ++mt) {
        int r = wm * 32 + mt * 16 + c16;
        int byt = r * 128 + (((kh * 4 + g) ^ (r & 7)) << 4);
        af[mt] = *(const bf16x8*)((const char*)lA + byt);
      }
#pragma unroll
      for (int nt = 0; nt < 8; ++nt) {
        int n = wn * 128 + nt * 16 + c16;
        int byt = n * 128 + (((kh * 4 + g) ^ (n & 7)) << 4);
        bfr[nt] = *(const bf16x8*)((const char*)lB + byt);
      }
#pragma unroll
      for (int mt = 0; mt < 2; ++mt)
#pragma unroll
        for (int nt = 0; nt < 8; ++nt)
          acc[mt][nt] = __builtin_amdgcn_mfma_f32_16x16x32_bf16(
              af[mt], bfr[nt], acc[mt][nt], 0, 0, 0);
    }
    __syncthreads();
  }

  // ---- epilogue ----
  const int colbase = wn * 128;
  const float* bp = (id == 0) ? bDu : (id == 1) ? bDr1 : bDr2;
  float bias[8];
#pragma unroll
  for (int nt = 0; nt < 8; ++nt) bias[nt] = bp[colbase + nt * 16 + c16];

  if (id == 0) {
#pragma unroll
    for (int mt = 0; mt < 2; ++mt)
#pragma unroll
      for (int i = 0; i < 4; ++i) {
        int row = m0 + wm * 32 + mt * 16 + g * 4 + i;
        float* op = uP + (size_t)row * H_N + colbase + c16;
#pragma unroll
        for (int nt = 0; nt < 8; ++nt)
          op[nt * 16] = tanhf(acc[mt][nt][i] + bias[nt]);
      }
  } else {
    unsigned short* rP = (id == 1) ? r1P : r2P;
    float rmx[2][4];
#pragma unroll
    for (int mt = 0; mt < 2; ++mt)
#pragma unroll
      for (int i = 0; i < 4; ++i) {
        float m = -3.0e38f;
#pragma unroll
        for (int nt = 0; nt < 8; ++nt) m = fmaxf(m, acc[mt][nt][i] + bias[nt]);
        m = fmaxf(m, __shfl_xor(m, 1));
        m = fmaxf(m, __shfl_xor(m, 2));
        m = fmaxf(m, __shfl_xor(m, 4));
        m = fmaxf(m, __shfl_xor(m, 8));
        rmx[mt][i] = m;
        if (c16 == 0) red[wm * 32 + mt * 16 + g * 4 + i][wn] = m;
      }
    __syncthreads();
#pragma unroll
    for (int mt = 0; mt < 2; ++mt)
#pragma unroll
      for (int i = 0; i < 4; ++i) {
        int rl = wm * 32 + mt * 16 + g * 4 + i;
        float4 q = *(const float4*)red[rl];
        float m = fmaxf(fmaxf(q.x, q.y), fmaxf(q.z, q.w));
        rmx[mt][i] = m;
        float s = 0.f;
#pragma unroll
        for (int nt = 0; nt < 8; ++nt) {
          float e = __expf(acc[mt][nt][i] + bias[nt] - m);
          acc[mt][nt][i] = e;
          s += e;
        }
        s += __shfl_xor(s, 1);
        s += __shfl_xor(s, 2);
        s += __shfl_xor(s, 4);
        s += __shfl_xor(s, 8);
        if (c16 == 0) red2[rl][wn] = s;
      }
    __syncthreads();
#pragma unroll
    for (int mt = 0; mt < 2; ++mt)
#pragma unroll
      for (int i = 0; i < 4; ++i) {
        int rl = wm * 32 + mt * 16 + g * 4 + i;
        float4 q = *(const float4*)red2[rl];
        float inv = 1.f / (q.x + q.y + q.z + q.w);
        int row = m0 + rl;
        unsigned short* op = rP + (size_t)row * H_N + colbase + c16;
#pragma unroll
        for (int nt = 0; nt < 8; ++nt)
          op[nt * 16] = f2bf(acc[mt][nt][i] * inv);
      }
  }
}

// ---------------------------------------------------------------------------
// Chunked linear-recurrence scan: s_t = r1_t * s_{t-1} + r2_t * u_t.
// 8 chunks of 64 steps -> 131072 parallel threads in passes 1/3.
// ---------------------------------------------------------------------------
__global__ void scan_pass1(const unsigned short* __restrict__ r1P,
                           const unsigned short* __restrict__ r2P,
                           const float* __restrict__ uP,
                           float* __restrict__ cP,
                           float* __restrict__ cS) {
  int gt = blockIdx.x * 256 + threadIdx.x;  // 0..131071
  int chunk = gt >> 14;
  int r = gt & 16383;
  int b = r >> 9, h = r & 511;
  size_t idx = (size_t)b * (T_N * H_N) + (size_t)(chunk * 64) * H_N + h;
  float p = 1.f, s = 0.f;
#pragma unroll 4
  for (int j = 0; j < 64; ++j) {
    float a = bf2f(r1P[idx]);
    float c = bf2f(r2P[idx]);
    float uu = uP[idx];
    s = fmaf(a, s, c * uu);
    p *= a;
    idx += H_N;
  }
  cP[gt] = p;
  cS[gt] = s;
}

__global__ void scan_pass2(const float* __restrict__ cP,
                           const float* __restrict__ cS,
                           float* __restrict__ carry) {
  int r = blockIdx.x * 256 + threadIdx.x;  // 0..16383
  float s = 0.f;
#pragma unroll
  for (int c = 0; c < 8; ++c) {
    carry[c * 16384 + r] = s;
    s = fmaf(cP[c * 16384 + r], s, cS[c * 16384 + r]);
  }
}

__global__ void scan_pass3(const unsigned short* __restrict__ r1P,
                           const unsigned short* __restrict__ r2P,
                           const float* __restrict__ uP,
                           const float* __restrict__ carry,
                           float* __restrict__ out) {
  int gt = blockIdx.x * 256 + threadIdx.x;
  int chunk = gt >> 14;
  int r = gt & 16383;
  int b = r >> 9, h = r & 511;
  size_t idx = (size_t)b * (T_N * H_N) + (size_t)(chunk * 64) * H_N + h;
  float s = carry[gt];
#pragma unroll 4
  for (int j = 0; j < 64; ++j) {
    float a = bf2f(r1P[idx]);
    float c = bf2f(r2P[idx]);
    float uu = uP[idx];
    s = fmaf(a, s, c * uu);
    out[idx] = s;
    idx += H_N;
  }
}

extern "C" void kernel_launch(void* const* d_in, const int* in_sizes, int n_in,
                              void* d_out, int out_size, void* d_ws, size_t ws_size,
                              hipStream_t stream) {
  const float* x  = (const float*)d_in[0];
  const float* W0 = (const float*)d_in[1];
  const float* W1 = (const float*)d_in[2];
  const float* W2 = (const float*)d_in[3];
  const float* b0 = (const float*)d_in[4];
  const float* b1 = (const float*)d_in[5];
  const float* b2 = (const float*)d_in[6];
  float* out = (float*)d_out;

  char* ws = (char*)d_ws;
  unsigned short* xb  = (unsigned short*)ws;                  // 16 MB  bf16 x
  unsigned short* Wt  = (unsigned short*)(ws + 16777216);     // 1.5 MB bf16 W^T x3
  float*          uP  = (float*)(ws + 18350080);              // 32 MB  f32 u
  unsigned short* r1P = (unsigned short*)(ws + 51904512);     // 16 MB  bf16 r1
  unsigned short* r2P = (unsigned short*)(ws + 68681728);     // 16 MB  bf16 r2
  float*          cP  = (float*)(ws + 85458944);              // 0.5 MB chunk prod
  float*          cS  = (float*)(ws + 85983232);              // 0.5 MB chunk partial
  float*          cy  = (float*)(ws + 86507520);              // 0.5 MB carries
  // total 87,031,808 bytes

  prep_kernel<<<2816, 256, 0, stream>>>(x, W0, W1, W2, xb, Wt);
  gemm_act<<<dim3(256, 3), 512, 0, stream>>>(xb, Wt, b0, b1, b2, uP, r1P, r2P);
  scan_pass1<<<512, 256, 0, stream>>>(r1P, r2P, uP, cP, cS);
  scan_pass2<<<64, 256, 0, stream>>>(cP, cS, cy);
  scan_pass3<<<512, 256, 0, stream>>>(r1P, r2P, uP, cy, out);
}

// Round 3
// 96.850 us; speedup vs baseline: 1.0634x; 1.0634x over previous
//
#include <hip/hip_runtime.h>
#include <hip/hip_bf16.h>

#define B_N 32
#define T_N 512
#define D_N 512
#define H_N 512
#define M_N (B_N * T_N)   // 16384

typedef __attribute__((ext_vector_type(8))) short bf16x8;
typedef __attribute__((ext_vector_type(4))) float f32x4;

__device__ __forceinline__ unsigned short f2bf(float f) {
  unsigned u = __float_as_uint(f);
  u += 0x7FFFu + ((u >> 16) & 1u);   // RTNE
  return (unsigned short)(u >> 16);
}
__device__ __forceinline__ float bf2f(unsigned short h) {
  return __uint_as_float(((unsigned)h) << 16);
}

#define GLOAD16(g, l) __builtin_amdgcn_global_load_lds( \
    (const __attribute__((address_space(1))) void*)(g), \
    (__attribute__((address_space(3))) void*)(l), 16, 0, 0)

// ---------------------------------------------------------------------------
// prep: blocks [0,768) transpose+convert the 3 weight matrices (W[k][n] ->
// Wt[id][n][k] bf16); blocks [768, 2816) convert x f32 -> bf16.
// ---------------------------------------------------------------------------
__global__ void prep_kernel(const float* __restrict__ x,
                            const float* __restrict__ W0,
                            const float* __restrict__ W1,
                            const float* __restrict__ W2,
                            unsigned short* __restrict__ xb,
                            unsigned short* __restrict__ Wt) {
  int blk = blockIdx.x;
  int tid = threadIdx.x;
  if (blk < 768) {
    __shared__ float tile[32][33];
    int id = blk >> 8;
    int t = blk & 255;
    int kr = (t >> 4) << 5;
    int nc = (t & 15) << 5;
    const float* W = (id == 0) ? W0 : (id == 1) ? W1 : W2;
    unsigned short* Wo = Wt + (size_t)id * (D_N * H_N);
    int tx = tid & 31, ty0 = tid >> 5;
    for (int ty = ty0; ty < 32; ty += 8)
      tile[ty][tx] = W[(size_t)(kr + ty) * H_N + nc + tx];
    __syncthreads();
    for (int ty = ty0; ty < 32; ty += 8)
      Wo[(size_t)(nc + ty) * D_N + kr + tx] = f2bf(tile[tx][ty]);
  } else {
    int b = blk - 768;
    const float4* xv = (const float4*)x;
#pragma unroll
    for (int u = 0; u < 4; ++u) {
      int i = b * 1024 + u * 256 + tid;
      float4 v = xv[i];
      ushort4 o;
      o.x = f2bf(v.x); o.y = f2bf(v.y); o.z = f2bf(v.z); o.w = f2bf(v.w);
      ((ushort4*)xb)[i] = o;
    }
  }
}

// ---------------------------------------------------------------------------
// gemm_act v2: BM=64 x full N=512, BK=64, 8 waves each owning a 64x64 tile
// (wave wv -> cols [wv*64, wv*64+64)).  Double-buffered LDS (144 KB, 1
// block/CU, grid=768 = exactly 3 blocks/CU) with the T3 2-phase schedule:
// issue next K-step's global_load_lds, compute current, then vmcnt(0)+barrier.
// XOR-swizzled LDS (pre-swizzled global source, swizzled ds_read) -- 0 bank
// conflicts, verified in v1.  Epilogue fuses bias + tanh / softmax; the
// cross-wave reduction arrays alias the first 4 KB of buf0's A-tile.
// ---------------------------------------------------------------------------
__global__ __launch_bounds__(512) void gemm_act(
    const unsigned short* __restrict__ xb,
    const unsigned short* __restrict__ Wt,
    const float* __restrict__ bDu,
    const float* __restrict__ bDr1,
    const float* __restrict__ bDr2,
    float* __restrict__ uP,
    unsigned short* __restrict__ r1P,
    unsigned short* __restrict__ r2P) {
  // layout: lA[buf] at 0 / 8192 (each 64x64 bf16 = 8KB)
  //         lB[buf] at 16384 / 81920 (each 512x64 bf16 = 64KB)
  __shared__ __align__(16) char smem[147456];

  const int tid = threadIdx.x;
  const int lane = tid & 63;
  const int wv = tid >> 6;      // 0..7 -> column strip
  const int g = lane >> 4;      // 0..3
  const int c16 = lane & 15;

  const int m0 = blockIdx.x * 64;
  const int id = blockIdx.y;
  const unsigned short* Wp = Wt + (size_t)id * (D_N * H_N);

  f32x4 acc[4][4];
#pragma unroll
  for (int mt = 0; mt < 4; ++mt)
#pragma unroll
    for (int nt = 0; nt < 4; ++nt)
      acc[mt][nt] = (f32x4){0.f, 0.f, 0.f, 0.f};

  // --- staging addresses (pre-swizzled global source, linear LDS dest) ---
  // A: 512 16B-chunks; chunk cw = wv*64+lane -> row cw>>3, swizzled k-slot.
  const int sl = ((lane & 7) ^ (lane >> 3)) << 3;   // swizzled slot (elems)
  const unsigned short* aSrc =
      xb + (size_t)(m0 + wv * 8 + (lane >> 3)) * D_N + sl;
  const unsigned short* bSrc0 =
      Wp + (size_t)(wv * 64 + (lane >> 3)) * D_N + sl;
  const int aDst = wv * 1024;   // byte offset inside lA[buf]
  const int bDst = wv * 8192;   // byte offset inside lB[buf]

#define STAGE(buf, kstep) do {                                          \
    const int k0_ = (kstep) * 64;                                       \
    GLOAD16(aSrc + k0_, smem + (buf) * 8192 + aDst);                    \
    _Pragma("unroll")                                                   \
    for (int jj = 0; jj < 8; ++jj)                                      \
      GLOAD16(bSrc0 + jj * 4096 + k0_,                                  \
              smem + 16384 + (buf) * 65536 + bDst + jj * 1024);         \
  } while (0)

#define COMPUTE(buf) do {                                               \
    _Pragma("unroll")                                                   \
    for (int kh = 0; kh < 2; ++kh) {                                    \
      bf16x8 af[4], bb[4];                                              \
      _Pragma("unroll")                                                 \
      for (int mt = 0; mt < 4; ++mt) {                                  \
        int r = mt * 16 + c16;                                          \
        af[mt] = *(const bf16x8*)(smem + (buf) * 8192 + r * 128 +       \
                                  (((kh * 4 + g) ^ (r & 7)) << 4));     \
      }                                                                 \
      _Pragma("unroll")                                                 \
      for (int nt = 0; nt < 4; ++nt) {                                  \
        int n = wv * 64 + nt * 16 + c16;                                \
        bb[nt] = *(const bf16x8*)(smem + 16384 + (buf) * 65536 +        \
                                  n * 128 +                             \
                                  (((kh * 4 + g) ^ (n & 7)) << 4));     \
      }                                                                 \
      _Pragma("unroll")                                                 \
      for (int mt = 0; mt < 4; ++mt)                                    \
        _Pragma("unroll")                                               \
        for (int nt = 0; nt < 4; ++nt)                                  \
          acc[mt][nt] = __builtin_amdgcn_mfma_f32_16x16x32_bf16(        \
              af[mt], bb[nt], acc[mt][nt], 0, 0, 0);                    \
    }                                                                   \
  } while (0)

  STAGE(0, 0);
#pragma unroll
  for (int kk = 0; kk < 8; kk += 2) {
    asm volatile("s_waitcnt vmcnt(0)" ::: "memory");
    __syncthreads();
    STAGE(1, kk + 1);
    COMPUTE(0);
    asm volatile("s_waitcnt vmcnt(0)" ::: "memory");
    __syncthreads();
    if (kk + 2 < 8) STAGE(0, kk + 2);
    COMPUTE(1);
  }

  // ---- epilogue ----
  const int colbase = wv * 64;
  const float* bp = (id == 0) ? bDu : (id == 1) ? bDr1 : bDr2;
  float bias[4];
#pragma unroll
  for (int nt = 0; nt < 4; ++nt) bias[nt] = bp[colbase + nt * 16 + c16];

  if (id == 0) {
#pragma unroll
    for (int mt = 0; mt < 4; ++mt)
#pragma unroll
      for (int i = 0; i < 4; ++i) {
        int row = m0 + mt * 16 + g * 4 + i;
        float* op = uP + (size_t)row * H_N + colbase + c16;
#pragma unroll
        for (int nt = 0; nt < 4; ++nt)
          op[nt * 16] = tanhf(acc[mt][nt][i] + bias[nt]);
      }
  } else {
    // reduction scratch aliases buf0 A-tile (bytes 0..4096; K-loop is done
    // with buf0, and stragglers only read buf1 / lB regions -- disjoint).
    float* red  = (float*)smem;           // [64][8]
    float* red2 = (float*)(smem + 2048);  // [64][8]
    unsigned short* rP = (id == 1) ? r1P : r2P;
#pragma unroll
    for (int mt = 0; mt < 4; ++mt)
#pragma unroll
      for (int i = 0; i < 4; ++i) {
        float m = -3.0e38f;
#pragma unroll
        for (int nt = 0; nt < 4; ++nt) m = fmaxf(m, acc[mt][nt][i] + bias[nt]);
        m = fmaxf(m, __shfl_xor(m, 1));
        m = fmaxf(m, __shfl_xor(m, 2));
        m = fmaxf(m, __shfl_xor(m, 4));
        m = fmaxf(m, __shfl_xor(m, 8));
        if (c16 == 0) red[(mt * 16 + g * 4 + i) * 8 + wv] = m;
      }
    __syncthreads();
#pragma unroll
    for (int mt = 0; mt < 4; ++mt)
#pragma unroll
      for (int i = 0; i < 4; ++i) {
        int rl = mt * 16 + g * 4 + i;
        float4 q0 = *(const float4*)(red + rl * 8);
        float4 q1 = *(const float4*)(red + rl * 8 + 4);
        float m = fmaxf(fmaxf(fmaxf(q0.x, q0.y), fmaxf(q0.z, q0.w)),
                        fmaxf(fmaxf(q1.x, q1.y), fmaxf(q1.z, q1.w)));
        float s = 0.f;
#pragma unroll
        for (int nt = 0; nt < 4; ++nt) {
          float e = __expf(acc[mt][nt][i] + bias[nt] - m);
          acc[mt][nt][i] = e;
          s += e;
        }
        s += __shfl_xor(s, 1);
        s += __shfl_xor(s, 2);
        s += __shfl_xor(s, 4);
        s += __shfl_xor(s, 8);
        if (c16 == 0) red2[rl * 8 + wv] = s;
      }
    __syncthreads();
#pragma unroll
    for (int mt = 0; mt < 4; ++mt)
#pragma unroll
      for (int i = 0; i < 4; ++i) {
        int rl = mt * 16 + g * 4 + i;
        float4 q0 = *(const float4*)(red2 + rl * 8);
        float4 q1 = *(const float4*)(red2 + rl * 8 + 4);
        float inv = 1.f / (q0.x + q0.y + q0.z + q0.w + q1.x + q1.y + q1.z + q1.w);
        unsigned short* op = rP + (size_t)(m0 + rl) * H_N + colbase + c16;
#pragma unroll
        for (int nt = 0; nt < 4; ++nt)
          op[nt * 16] = f2bf(acc[mt][nt][i] * inv);
      }
  }
#undef STAGE
#undef COMPUTE
}

// ---------------------------------------------------------------------------
// Chunked linear-recurrence scan: s_t = r1_t * s_{t-1} + r2_t * u_t.
// 8 chunks of 64 steps; pass3 composes its own carry from cP/cS (pass2 fused).
// ---------------------------------------------------------------------------
__global__ void scan_pass1(const unsigned short* __restrict__ r1P,
                           const unsigned short* __restrict__ r2P,
                           const float* __restrict__ uP,
                           float* __restrict__ cP,
                           float* __restrict__ cS) {
  int gt = blockIdx.x * 256 + threadIdx.x;  // 0..131071
  int chunk = gt >> 14;
  int r = gt & 16383;
  int b = r >> 9, h = r & 511;
  size_t idx = (size_t)b * (T_N * H_N) + (size_t)(chunk * 64) * H_N + h;
  float p = 1.f, s = 0.f;
#pragma unroll 4
  for (int j = 0; j < 64; ++j) {
    float a = bf2f(r1P[idx]);
    float c = bf2f(r2P[idx]);
    float uu = uP[idx];
    s = fmaf(a, s, c * uu);
    p *= a;
    idx += H_N;
  }
  cP[gt] = p;
  cS[gt] = s;
}

__global__ void scan_pass3(const unsigned short* __restrict__ r1P,
                           const unsigned short* __restrict__ r2P,
                           const float* __restrict__ uP,
                           const float* __restrict__ cP,
                           const float* __restrict__ cS,
                           float* __restrict__ out) {
  int gt = blockIdx.x * 256 + threadIdx.x;
  int chunk = gt >> 14;
  int r = gt & 16383;
  int b = r >> 9, h = r & 511;
  // carry: compose preceding chunks (uniform trip count per block)
  float s = 0.f;
  for (int c2 = 0; c2 < chunk; ++c2)
    s = fmaf(cP[c2 * 16384 + r], s, cS[c2 * 16384 + r]);
  size_t idx = (size_t)b * (T_N * H_N) + (size_t)(chunk * 64) * H_N + h;
#pragma unroll 4
  for (int j = 0; j < 64; ++j) {
    float a = bf2f(r1P[idx]);
    float c = bf2f(r2P[idx]);
    float uu = uP[idx];
    s = fmaf(a, s, c * uu);
    out[idx] = s;
    idx += H_N;
  }
}

extern "C" void kernel_launch(void* const* d_in, const int* in_sizes, int n_in,
                              void* d_out, int out_size, void* d_ws, size_t ws_size,
                              hipStream_t stream) {
  const float* x  = (const float*)d_in[0];
  const float* W0 = (const float*)d_in[1];
  const float* W1 = (const float*)d_in[2];
  const float* W2 = (const float*)d_in[3];
  const float* b0 = (const float*)d_in[4];
  const float* b1 = (const float*)d_in[5];
  const float* b2 = (const float*)d_in[6];
  float* out = (float*)d_out;

  char* ws = (char*)d_ws;
  unsigned short* xb  = (unsigned short*)ws;                  // 16 MB  bf16 x
  unsigned short* Wt  = (unsigned short*)(ws + 16777216);     // 1.5 MB bf16 W^T x3
  float*          uP  = (float*)(ws + 18350080);              // 32 MB  f32 u
  unsigned short* r1P = (unsigned short*)(ws + 51904512);     // 16 MB  bf16 r1
  unsigned short* r2P = (unsigned short*)(ws + 68681728);     // 16 MB  bf16 r2
  float*          cP  = (float*)(ws + 85458944);              // 0.5 MB chunk prod
  float*          cS  = (float*)(ws + 85983232);              // 0.5 MB chunk partial
  // total 86,507,520 bytes

  prep_kernel<<<2816, 256, 0, stream>>>(x, W0, W1, W2, xb, Wt);
  gemm_act<<<dim3(256, 3), 512, 0, stream>>>(xb, Wt, b0, b1, b2, uP, r1P, r2P);
  scan_pass1<<<512, 256, 0, stream>>>(r1P, r2P, uP, cP, cS);
  scan_pass3<<<512, 256, 0, stream>>>(r1P, r2P, uP, cP, cS, out);
}